// Round 11
// baseline (136.873 us; speedup 1.0000x reference)
//
#include <hip/hip_runtime.h>
#include <hip/hip_bf16.h>

#define BATCH 2048
#define NNODES 512
#define HID 64
#define LN_EPS 1e-5f
#define NEG_SLOPE 0.01f

#define NPB 4        // nodes per block (one per wave; waves fully independent)
#define SUBS 8       // 16-row subtiles per wave
#define RPW 128      // rows per wave = SUBS*16

typedef __attribute__((ext_vector_type(8))) short bf16x8;
typedef __attribute__((ext_vector_type(4))) float f32x4;

__device__ __forceinline__ short f2bf(float f) {
    union { __hip_bfloat16 h; short s; } u;
    u.h = __float2bfloat16(f);   // canonical RNE (R3/R4-verified)
    return u.s;
}

#define WAITV4() asm volatile("s_waitcnt vmcnt(4)" ::: "memory")
#define WAITV8() asm volatile("s_waitcnt vmcnt(8)" ::: "memory")
#define WAITL0() asm volatile("s_waitcnt lgkmcnt(0)" ::: "memory")

// v11 = R10 (101.3us) + LDS diet for occupancy:
//  - tLds ALIASED into the just-consumed xStage buffer (x ds_reads retire
//    before the repack write; buffer is dead until STAGE(sub+2), which waits
//    lgkmcnt(0) after the epilogue reads). Repack rows are 64 floats with
//    XOR swizzle col^((row&7)<<2) -> minimal bank conflicts both sides.
//  - mu/rstd broadcast via __shfl (8 bpermutes) instead of LDS scalars.
//  - sfac folded into W convert (t = x @ (s*W)^T): 32 VALU/sub -> 16 once.
// Total LDS = 32KB exactly -> >=4 blocks/CU (5 if VGPR<=102).
// vmcnt ledger unchanged from R10: 4 gll + 4 NT stores per sub;
// N=4 at sub 0/SUBS-1, else 8.
__global__ __launch_bounds__(256, 4) void wv_mfma9_kernel(
    const float* __restrict__ x,      // [B, N, H]
    const float* __restrict__ dec,    // [3, 4]
    const float* __restrict__ rec,    // [3, 4]
    const float* __restrict__ W,      // [N, H, H]
    const float* __restrict__ bias,   // [N, H]
    const float* __restrict__ gamma,  // [N, H]
    const float* __restrict__ beta,   // [N, H]
    const int*   __restrict__ scales, // [N]
    float* __restrict__ out)          // [B, N, H]
{
    __shared__ float xStage[NPB][2][1024];   // 2 x 4KB per wave; 32KB total

    const int tid  = threadIdx.x;
    const int wave = tid >> 6;
    const int lane = tid & 63;
    const int l16  = lane & 15;
    const int lg   = lane >> 4;      // 0..3

    const int ng   = blockIdx.x & 127;   // node-group minor (R7 lesson)
    const int rc   = blockIdx.x >> 7;    // 0..15 row chunk
    const int node = ng * NPB + wave;
    const int b0   = rc * RPW;

    const int   sc   = scales[node];
    const float sfac = dec[sc * 4 + 1] + rec[sc * 4 + 1];

// stage rows b0+(sub)*16..+15 into xStage[wave][buf]; lane j covers row
// k*4+(j>>4), 16B slot (j&15); source col pre-swizzled so LDS reads with the
// same XOR are bank-spread (rule #21 both-sides). 4 x gll_dwordx4 (1KB each).
#define STAGE(sub_, buf_)                                                     \
    {                                                                         \
        const int s4_ = (lane & 15) * 4;                                      \
        const int rb_ = lane >> 4;                                            \
        _Pragma("unroll")                                                     \
        for (int k_ = 0; k_ < 4; ++k_) {                                      \
            const int r_ = k_ * 4 + rb_;                                      \
            const float* g_ = x + (size_t)(b0 + (sub_) * 16 + r_) *           \
                                  (NNODES * HID) + node * HID +               \
                                  (s4_ ^ ((r_ & 7) << 2));                    \
            __builtin_amdgcn_global_load_lds(                                 \
                (const __attribute__((address_space(1))) void*)g_,            \
                (__attribute__((address_space(3))) void*)                     \
                    (&xStage[wave][buf_][0] + k_ * 256),                      \
                16, 0, 0);                                                    \
        }                                                                     \
    }

    // ---- prologue: W loads (16 dwordx4), then stage(0), stage(1)
    f32x4 wv[4][2][2];
    const float* Wn = W + (size_t)node * HID * HID;
    #pragma unroll
    for (int c = 0; c < 4; ++c) {
        #pragma unroll
        for (int s = 0; s < 2; ++s) {
            const float* p = Wn + (c * 16 + l16) * HID + s * 32 + lg * 8;
            wv[c][s][0] = *reinterpret_cast<const f32x4*>(p);
            wv[c][s][1] = *reinterpret_cast<const f32x4*>(p + 4);
        }
    }
    STAGE(0, 0);
    STAGE(1, 1);

    // ---- epilogue params
    f32x4 bb[4];
    #pragma unroll
    for (int c = 0; c < 4; ++c)
        bb[c] = *reinterpret_cast<const f32x4*>(bias + node * HID + c * 16 + lg * 4);
    const f32x4 gg = *reinterpret_cast<const f32x4*>(gamma + node * HID + l16 * 4);
    const f32x4 be = *reinterpret_cast<const f32x4*>(beta  + node * HID + l16 * 4);

    // ---- convert W once, sfac folded in (t = x @ (s*W)^T)
    bf16x8 wf[4][2];
    #pragma unroll
    for (int c = 0; c < 4; ++c) {
        #pragma unroll
        for (int s = 0; s < 2; ++s) {
            const f32x4 w0 = wv[c][s][0], w1 = wv[c][s][1];
            bf16x8 f;
            f[0] = f2bf(w0[0] * sfac); f[1] = f2bf(w0[1] * sfac);
            f[2] = f2bf(w0[2] * sfac); f[3] = f2bf(w0[3] * sfac);
            f[4] = f2bf(w1[0] * sfac); f[5] = f2bf(w1[1] * sfac);
            f[6] = f2bf(w1[2] * sfac); f[7] = f2bf(w1[3] * sfac);
            wf[c][s] = f;
        }
    }

    const int ro = l16 * 64;           // x-phase LDS row offset (floats)
    const int sw = (l16 & 7) << 2;     // x-phase read-side XOR (floats)

    #pragma unroll
    for (int sub = 0; sub < SUBS; ++sub) {
        // counted wait: stage(sub) retired when <= N newer vmem ops remain
        if (sub == 0 || sub == SUBS - 1) { WAITV4(); } else { WAITV8(); }

        float* Sb = &xStage[wave][sub & 1][0];
        const f32x4 x0 = *reinterpret_cast<const f32x4*>(Sb + ro + ((lg * 8     ) ^ sw));
        const f32x4 x1 = *reinterpret_cast<const f32x4*>(Sb + ro + ((lg * 8 + 4 ) ^ sw));
        const f32x4 x2 = *reinterpret_cast<const f32x4*>(Sb + ro + ((lg * 8 + 32) ^ sw));
        const f32x4 x3 = *reinterpret_cast<const f32x4*>(Sb + ro + ((lg * 8 + 36) ^ sw));

        bf16x8 af0, af1;
        af0[0] = f2bf(x0[0]); af0[1] = f2bf(x0[1]);
        af0[2] = f2bf(x0[2]); af0[3] = f2bf(x0[3]);
        af0[4] = f2bf(x1[0]); af0[5] = f2bf(x1[1]);
        af0[6] = f2bf(x1[2]); af0[7] = f2bf(x1[3]);
        af1[0] = f2bf(x2[0]); af1[1] = f2bf(x2[1]);
        af1[2] = f2bf(x2[2]); af1[3] = f2bf(x2[3]);
        af1[4] = f2bf(x3[0]); af1[5] = f2bf(x3[1]);
        af1[6] = f2bf(x3[2]); af1[7] = f2bf(x3[3]);

        f32x4 acc[4];
        #pragma unroll
        for (int c = 0; c < 4; ++c) {
            acc[c][0] = 0.f; acc[c][1] = 0.f; acc[c][2] = 0.f; acc[c][3] = 0.f;
            acc[c] = __builtin_amdgcn_mfma_f32_16x16x32_bf16(wf[c][0], af0, acc[c], 0, 0, 0);
            acc[c] = __builtin_amdgcn_mfma_f32_16x16x32_bf16(wf[c][1], af1, acc[c], 0, 0, 0);
        }

        // ---- +bias, two-pass LN in registers (R4/R6-verified)
        float pS = 0.f;
        #pragma unroll
        for (int c = 0; c < 4; ++c) {
            #pragma unroll
            for (int i = 0; i < 4; ++i) {
                acc[c][i] += bb[c][i];
                pS += acc[c][i];
            }
        }
        pS += __shfl_xor(pS, 16, 64);
        pS += __shfl_xor(pS, 32, 64);
        const float mu = pS * (1.0f / 64.0f);

        float qS = 0.f;
        #pragma unroll
        for (int c = 0; c < 4; ++c) {
            #pragma unroll
            for (int i = 0; i < 4; ++i) {
                const float d = acc[c][i] - mu;
                qS += d * d;
            }
        }
        qS += __shfl_xor(qS, 16, 64);
        qS += __shfl_xor(qS, 32, 64);
        const float rstd = 1.0f / sqrtf(qS * (1.0f / 64.0f) + LN_EPS);

        // ---- repack t into the CONSUMED x buffer (x reads already retired
        //      into registers before the cvt above). 64-float rows + XOR
        //      swizzle col^((row&7)<<2): minimal-conflict write and read.
        #pragma unroll
        for (int c = 0; c < 4; ++c)
            *reinterpret_cast<f32x4*>(
                Sb + l16 * 64 + ((c * 16 + lg * 4) ^ ((l16 & 7) << 2))) = acc[c];

        // ---- epilogue: lane (l16,lg) -> row rl=k*4+lg, cols l16*4..+3;
        //      mu/rstd fetched by shfl from the lane that owns row rl.
        const int rowb = b0 + sub * 16;
        #pragma unroll
        for (int k = 0; k < 4; ++k) {
            const int rl = k * 4 + lg;
            const f32x4 tv = *reinterpret_cast<const f32x4*>(
                Sb + rl * 64 + ((l16 * 4) ^ ((rl & 7) << 2)));
            const float m  = __shfl(mu,   rl, 64);
            const float rs = __shfl(rstd, rl, 64);
            f32x4 o;
            #pragma unroll
            for (int i = 0; i < 4; ++i) {
                float v = (tv[i] - m) * rs * gg[i] + be[i];
                o[i] = v >= 0.f ? v : v * NEG_SLOPE;
            }
            __builtin_nontemporal_store(
                o, reinterpret_cast<f32x4*>(
                       out + ((size_t)(rowb + rl) * NNODES + node) * HID + l16 * 4));
        }

        // ---- recycle: epilogue ds_reads must retire before gll overwrites
        WAITL0();
        if (sub + 2 < SUBS) {
            STAGE(sub + 2, sub & 1);
        }
    }
#undef STAGE
}

extern "C" void kernel_launch(void* const* d_in, const int* in_sizes, int n_in,
                              void* d_out, int out_size, void* d_ws, size_t ws_size,
                              hipStream_t stream) {
    const float* x      = (const float*)d_in[0];
    const float* dec    = (const float*)d_in[1];
    const float* rec    = (const float*)d_in[2];
    const float* W      = (const float*)d_in[3];
    const float* bias   = (const float*)d_in[4];
    const float* gamma  = (const float*)d_in[5];
    const float* beta   = (const float*)d_in[6];
    const int*   scales = (const int*)d_in[7];
    float* out = (float*)d_out;

    const int blocks = (NNODES / NPB) * (BATCH / RPW);  // 128 * 16 = 2048
    wv_mfma9_kernel<<<blocks, 256, 0, stream>>>(
        x, dec, rec, W, bias, gamma, beta, scales, out);
}

// Round 12
// 99.843 us; speedup vs baseline: 1.3709x; 1.3709x over previous
//
#include <hip/hip_runtime.h>
#include <hip/hip_bf16.h>

#define BATCH 2048
#define NNODES 512
#define HID 64
#define LN_EPS 1e-5f
#define NEG_SLOPE 0.01f

#define NPB 4        // nodes per block (one per wave; waves fully independent)
#define SUBS 8       // 16-row subtiles per wave
#define RPW 128      // rows per wave = SUBS*16

typedef __attribute__((ext_vector_type(8))) short bf16x8;
typedef __attribute__((ext_vector_type(4))) float f32x4;

__device__ __forceinline__ short f2bf(float f) {
    union { __hip_bfloat16 h; short s; } u;
    u.h = __float2bfloat16(f);   // canonical RNE (R3/R4-verified)
    return u.s;
}

#define WAITV4() asm volatile("s_waitcnt vmcnt(4)" ::: "memory")
#define WAITV8() asm volatile("s_waitcnt vmcnt(8)" ::: "memory")
#define WAITL0() asm volatile("s_waitcnt lgkmcnt(0)" ::: "memory")

// v12 = R10 (101.3us, verified) + ONE change: tLds aliased into the
// just-consumed xStage buffer (R11's XOR-swizzle repack, which passed
// correctness). Everything else is R10-verbatim: muLds/rsLds LDS scalars,
// sfac applied on the x path, launch_bounds(256,3), same vmcnt ledger
// (4 gll + 4 NT stores per sub; N=4 at sub 0/SUBS-1 else 8; lgkmcnt(0)
// before each STAGE recycle). LDS 50688 -> 33280 B => 4 blocks/CU
// (launch_bounds 2nd arg is a MIN, not a cap, so occupancy rises free).
__global__ __launch_bounds__(256, 3) void wv_mfma10_kernel(
    const float* __restrict__ x,      // [B, N, H]
    const float* __restrict__ dec,    // [3, 4]
    const float* __restrict__ rec,    // [3, 4]
    const float* __restrict__ W,      // [N, H, H]
    const float* __restrict__ bias,   // [N, H]
    const float* __restrict__ gamma,  // [N, H]
    const float* __restrict__ beta,   // [N, H]
    const int*   __restrict__ scales, // [N]
    float* __restrict__ out)          // [B, N, H]
{
    __shared__ float xStage[NPB][2][1024];   // 2 x 4KB per wave; t aliased in
    __shared__ float muLds [NPB][16];
    __shared__ float rsLds [NPB][16];

    const int tid  = threadIdx.x;
    const int wave = tid >> 6;
    const int lane = tid & 63;
    const int l16  = lane & 15;
    const int lg   = lane >> 4;      // 0..3

    const int ng   = blockIdx.x & 127;   // node-group minor (R7 lesson)
    const int rc   = blockIdx.x >> 7;    // 0..15 row chunk
    const int node = ng * NPB + wave;
    const int b0   = rc * RPW;

    const int   sc   = scales[node];
    const float sfac = dec[sc * 4 + 1] + rec[sc * 4 + 1];

// stage rows b0+(sub)*16..+15 into xStage[wave][buf]; lane j covers row
// k*4+(j>>4), 16B slot (j&15); source col pre-swizzled so LDS reads with the
// same XOR are bank-spread (rule #21 both-sides). 4 x gll_dwordx4 (1KB each).
#define STAGE(sub_, buf_)                                                     \
    {                                                                         \
        const int s4_ = (lane & 15) * 4;                                      \
        const int rb_ = lane >> 4;                                            \
        _Pragma("unroll")                                                     \
        for (int k_ = 0; k_ < 4; ++k_) {                                      \
            const int r_ = k_ * 4 + rb_;                                      \
            const float* g_ = x + (size_t)(b0 + (sub_) * 16 + r_) *           \
                                  (NNODES * HID) + node * HID +               \
                                  (s4_ ^ ((r_ & 7) << 2));                    \
            __builtin_amdgcn_global_load_lds(                                 \
                (const __attribute__((address_space(1))) void*)g_,            \
                (__attribute__((address_space(3))) void*)                     \
                    (&xStage[wave][buf_][0] + k_ * 256),                      \
                16, 0, 0);                                                    \
        }                                                                     \
    }

    // ---- prologue: W loads (16 dwordx4), then stage(0), stage(1)
    f32x4 wv[4][2][2];
    const float* Wn = W + (size_t)node * HID * HID;
    #pragma unroll
    for (int c = 0; c < 4; ++c) {
        #pragma unroll
        for (int s = 0; s < 2; ++s) {
            const float* p = Wn + (c * 16 + l16) * HID + s * 32 + lg * 8;
            wv[c][s][0] = *reinterpret_cast<const f32x4*>(p);
            wv[c][s][1] = *reinterpret_cast<const f32x4*>(p + 4);
        }
    }
    STAGE(0, 0);
    STAGE(1, 1);

    // ---- epilogue params
    f32x4 bb[4];
    #pragma unroll
    for (int c = 0; c < 4; ++c)
        bb[c] = *reinterpret_cast<const f32x4*>(bias + node * HID + c * 16 + lg * 4);
    const f32x4 gg = *reinterpret_cast<const f32x4*>(gamma + node * HID + l16 * 4);
    const f32x4 be = *reinterpret_cast<const f32x4*>(beta  + node * HID + l16 * 4);

    // ---- convert W once (compiler's own vmcnt wait covers the W loads)
    bf16x8 wf[4][2];
    #pragma unroll
    for (int c = 0; c < 4; ++c) {
        #pragma unroll
        for (int s = 0; s < 2; ++s) {
            const f32x4 w0 = wv[c][s][0], w1 = wv[c][s][1];
            bf16x8 f;
            f[0] = f2bf(w0[0]); f[1] = f2bf(w0[1]); f[2] = f2bf(w0[2]); f[3] = f2bf(w0[3]);
            f[4] = f2bf(w1[0]); f[5] = f2bf(w1[1]); f[6] = f2bf(w1[2]); f[7] = f2bf(w1[3]);
            wf[c][s] = f;
        }
    }

    const int ro = l16 * 64;           // x-phase LDS row offset (floats)
    const int sw = (l16 & 7) << 2;     // x-phase read-side XOR (floats)

    #pragma unroll
    for (int sub = 0; sub < SUBS; ++sub) {
        // counted wait: stage(sub) retired when <= N newer vmem ops remain
        if (sub == 0 || sub == SUBS - 1) { WAITV4(); } else { WAITV8(); }

        float* Sb = &xStage[wave][sub & 1][0];
        const f32x4 x0 = *reinterpret_cast<const f32x4*>(Sb + ro + ((lg * 8     ) ^ sw));
        const f32x4 x1 = *reinterpret_cast<const f32x4*>(Sb + ro + ((lg * 8 + 4 ) ^ sw));
        const f32x4 x2 = *reinterpret_cast<const f32x4*>(Sb + ro + ((lg * 8 + 32) ^ sw));
        const f32x4 x3 = *reinterpret_cast<const f32x4*>(Sb + ro + ((lg * 8 + 36) ^ sw));

        bf16x8 af0, af1;
        af0[0] = f2bf(x0[0] * sfac); af0[1] = f2bf(x0[1] * sfac);
        af0[2] = f2bf(x0[2] * sfac); af0[3] = f2bf(x0[3] * sfac);
        af0[4] = f2bf(x1[0] * sfac); af0[5] = f2bf(x1[1] * sfac);
        af0[6] = f2bf(x1[2] * sfac); af0[7] = f2bf(x1[3] * sfac);
        af1[0] = f2bf(x2[0] * sfac); af1[1] = f2bf(x2[1] * sfac);
        af1[2] = f2bf(x2[2] * sfac); af1[3] = f2bf(x2[3] * sfac);
        af1[4] = f2bf(x3[0] * sfac); af1[5] = f2bf(x3[1] * sfac);
        af1[6] = f2bf(x3[2] * sfac); af1[7] = f2bf(x3[3] * sfac);

        f32x4 acc[4];
        #pragma unroll
        for (int c = 0; c < 4; ++c) {
            acc[c][0] = 0.f; acc[c][1] = 0.f; acc[c][2] = 0.f; acc[c][3] = 0.f;
            acc[c] = __builtin_amdgcn_mfma_f32_16x16x32_bf16(wf[c][0], af0, acc[c], 0, 0, 0);
            acc[c] = __builtin_amdgcn_mfma_f32_16x16x32_bf16(wf[c][1], af1, acc[c], 0, 0, 0);
        }

        // ---- +bias, two-pass LN in registers (R4/R6-verified)
        float pS = 0.f;
        #pragma unroll
        for (int c = 0; c < 4; ++c) {
            #pragma unroll
            for (int i = 0; i < 4; ++i) {
                acc[c][i] += bb[c][i];
                pS += acc[c][i];
            }
        }
        pS += __shfl_xor(pS, 16, 64);
        pS += __shfl_xor(pS, 32, 64);
        const float mu = pS * (1.0f / 64.0f);

        float qS = 0.f;
        #pragma unroll
        for (int c = 0; c < 4; ++c) {
            #pragma unroll
            for (int i = 0; i < 4; ++i) {
                const float d = acc[c][i] - mu;
                qS += d * d;
            }
        }
        qS += __shfl_xor(qS, 16, 64);
        qS += __shfl_xor(qS, 32, 64);
        const float rstd = 1.0f / sqrtf(qS * (1.0f / 64.0f) + LN_EPS);

        // ---- repack t into the CONSUMED x buffer (x already in registers).
        //      64-float rows + XOR swizzle col^((row&7)<<2): conflict-free
        //      write and read (R11-verified correctness).
        #pragma unroll
        for (int c = 0; c < 4; ++c)
            *reinterpret_cast<f32x4*>(
                Sb + l16 * 64 + ((c * 16 + lg * 4) ^ ((l16 & 7) << 2))) = acc[c];
        if (lg == 0) { muLds[wave][l16] = mu; rsLds[wave][l16] = rstd; }

        // ---- NT full-line stores: lane (l16,lg) -> row rl=k*4+lg, cols l16*4..+3
        const int rowb = b0 + sub * 16;
        #pragma unroll
        for (int k = 0; k < 4; ++k) {
            const int rl = k * 4 + lg;
            const f32x4 tv = *reinterpret_cast<const f32x4*>(
                Sb + rl * 64 + ((l16 * 4) ^ ((rl & 7) << 2)));
            const float m  = muLds[wave][rl];
            const float rs = rsLds[wave][rl];
            f32x4 o;
            #pragma unroll
            for (int i = 0; i < 4; ++i) {
                float v = (tv[i] - m) * rs * gg[i] + be[i];
                o[i] = v >= 0.f ? v : v * NEG_SLOPE;
            }
            __builtin_nontemporal_store(
                o, reinterpret_cast<f32x4*>(
                       out + ((size_t)(rowb + rl) * NNODES + node) * HID + l16 * 4));
        }

        // ---- recycle: epilogue ds_reads must retire before gll overwrites
        WAITL0();
        if (sub + 2 < SUBS) {
            STAGE(sub + 2, sub & 1);
        }
    }
#undef STAGE
}

extern "C" void kernel_launch(void* const* d_in, const int* in_sizes, int n_in,
                              void* d_out, int out_size, void* d_ws, size_t ws_size,
                              hipStream_t stream) {
    const float* x      = (const float*)d_in[0];
    const float* dec    = (const float*)d_in[1];
    const float* rec    = (const float*)d_in[2];
    const float* W      = (const float*)d_in[3];
    const float* bias   = (const float*)d_in[4];
    const float* gamma  = (const float*)d_in[5];
    const float* beta   = (const float*)d_in[6];
    const int*   scales = (const int*)d_in[7];
    float* out = (float*)d_out;

    const int blocks = (NNODES / NPB) * (BATCH / RPW);  // 128 * 16 = 2048
    wv_mfma10_kernel<<<blocks, 256, 0, stream>>>(
        x, dec, rec, W, bias, gamma, beta, scales, out);
}

// Round 13
// 97.521 us; speedup vs baseline: 1.4035x; 1.0238x over previous
//
#include <hip/hip_runtime.h>
#include <hip/hip_bf16.h>

#define BATCH 2048
#define NNODES 512
#define HID 64
#define LN_EPS 1e-5f
#define NEG_SLOPE 0.01f

#define NPB 4        // nodes per block (one per wave; waves fully independent)
#define SUBS 16      // 16-row subtiles per wave
#define RPW 256      // rows per wave = SUBS*16

typedef __attribute__((ext_vector_type(8))) short bf16x8;
typedef __attribute__((ext_vector_type(4))) float f32x4;

__device__ __forceinline__ short f2bf(float f) {
    union { __hip_bfloat16 h; short s; } u;
    u.h = __float2bfloat16(f);   // canonical RNE (R3/R4-verified)
    return u.s;
}

#define WAITV4() asm volatile("s_waitcnt vmcnt(4)" ::: "memory")
#define WAITV8() asm volatile("s_waitcnt vmcnt(8)" ::: "memory")
#define WAITL0() asm volatile("s_waitcnt lgkmcnt(0)" ::: "memory")

// v13 = R12 (99.8us, verified) + ONE change: SUBS 8->16 (256 rows/wave).
// W load+convert amortized over 2x rows; grid 1024 blocks = exactly 4/CU.
// Everything else R12-verbatim: tLds aliased into consumed xStage buffer
// (XOR swizzle col^((row&7)<<2)), muLds/rsLds LDS scalars, sfac on x path,
// launch_bounds(256,3), vmcnt ledger {4 gll + 4 NT stores per sub; N=4 at
// sub 0/SUBS-1 else 8; lgkmcnt(0) before STAGE recycle}.
__global__ __launch_bounds__(256, 3) void wv_mfma11_kernel(
    const float* __restrict__ x,      // [B, N, H]
    const float* __restrict__ dec,    // [3, 4]
    const float* __restrict__ rec,    // [3, 4]
    const float* __restrict__ W,      // [N, H, H]
    const float* __restrict__ bias,   // [N, H]
    const float* __restrict__ gamma,  // [N, H]
    const float* __restrict__ beta,   // [N, H]
    const int*   __restrict__ scales, // [N]
    float* __restrict__ out)          // [B, N, H]
{
    __shared__ float xStage[NPB][2][1024];   // 2 x 4KB per wave; t aliased in
    __shared__ float muLds [NPB][16];
    __shared__ float rsLds [NPB][16];

    const int tid  = threadIdx.x;
    const int wave = tid >> 6;
    const int lane = tid & 63;
    const int l16  = lane & 15;
    const int lg   = lane >> 4;      // 0..3

    const int ng   = blockIdx.x & 127;   // node-group minor (R7 lesson)
    const int rc   = blockIdx.x >> 7;    // 0..7 row chunk
    const int node = ng * NPB + wave;
    const int b0   = rc * RPW;

    const int   sc   = scales[node];
    const float sfac = dec[sc * 4 + 1] + rec[sc * 4 + 1];

// stage rows b0+(sub)*16..+15 into xStage[wave][buf]; lane j covers row
// k*4+(j>>4), 16B slot (j&15); source col pre-swizzled so LDS reads with the
// same XOR are bank-spread (rule #21 both-sides). 4 x gll_dwordx4 (1KB each).
#define STAGE(sub_, buf_)                                                     \
    {                                                                         \
        const int s4_ = (lane & 15) * 4;                                      \
        const int rb_ = lane >> 4;                                            \
        _Pragma("unroll")                                                     \
        for (int k_ = 0; k_ < 4; ++k_) {                                      \
            const int r_ = k_ * 4 + rb_;                                      \
            const float* g_ = x + (size_t)(b0 + (sub_) * 16 + r_) *           \
                                  (NNODES * HID) + node * HID +               \
                                  (s4_ ^ ((r_ & 7) << 2));                    \
            __builtin_amdgcn_global_load_lds(                                 \
                (const __attribute__((address_space(1))) void*)g_,            \
                (__attribute__((address_space(3))) void*)                     \
                    (&xStage[wave][buf_][0] + k_ * 256),                      \
                16, 0, 0);                                                    \
        }                                                                     \
    }

    // ---- prologue: W loads (16 dwordx4), then stage(0), stage(1)
    f32x4 wv[4][2][2];
    const float* Wn = W + (size_t)node * HID * HID;
    #pragma unroll
    for (int c = 0; c < 4; ++c) {
        #pragma unroll
        for (int s = 0; s < 2; ++s) {
            const float* p = Wn + (c * 16 + l16) * HID + s * 32 + lg * 8;
            wv[c][s][0] = *reinterpret_cast<const f32x4*>(p);
            wv[c][s][1] = *reinterpret_cast<const f32x4*>(p + 4);
        }
    }
    STAGE(0, 0);
    STAGE(1, 1);

    // ---- epilogue params
    f32x4 bb[4];
    #pragma unroll
    for (int c = 0; c < 4; ++c)
        bb[c] = *reinterpret_cast<const f32x4*>(bias + node * HID + c * 16 + lg * 4);
    const f32x4 gg = *reinterpret_cast<const f32x4*>(gamma + node * HID + l16 * 4);
    const f32x4 be = *reinterpret_cast<const f32x4*>(beta  + node * HID + l16 * 4);

    // ---- convert W once (compiler's own vmcnt wait covers the W loads)
    bf16x8 wf[4][2];
    #pragma unroll
    for (int c = 0; c < 4; ++c) {
        #pragma unroll
        for (int s = 0; s < 2; ++s) {
            const f32x4 w0 = wv[c][s][0], w1 = wv[c][s][1];
            bf16x8 f;
            f[0] = f2bf(w0[0]); f[1] = f2bf(w0[1]); f[2] = f2bf(w0[2]); f[3] = f2bf(w0[3]);
            f[4] = f2bf(w1[0]); f[5] = f2bf(w1[1]); f[6] = f2bf(w1[2]); f[7] = f2bf(w1[3]);
            wf[c][s] = f;
        }
    }

    const int ro = l16 * 64;           // x-phase LDS row offset (floats)
    const int sw = (l16 & 7) << 2;     // x-phase read-side XOR (floats)

    #pragma unroll
    for (int sub = 0; sub < SUBS; ++sub) {
        // counted wait: stage(sub) retired when <= N newer vmem ops remain
        if (sub == 0 || sub == SUBS - 1) { WAITV4(); } else { WAITV8(); }

        float* Sb = &xStage[wave][sub & 1][0];
        const f32x4 x0 = *reinterpret_cast<const f32x4*>(Sb + ro + ((lg * 8     ) ^ sw));
        const f32x4 x1 = *reinterpret_cast<const f32x4*>(Sb + ro + ((lg * 8 + 4 ) ^ sw));
        const f32x4 x2 = *reinterpret_cast<const f32x4*>(Sb + ro + ((lg * 8 + 32) ^ sw));
        const f32x4 x3 = *reinterpret_cast<const f32x4*>(Sb + ro + ((lg * 8 + 36) ^ sw));

        bf16x8 af0, af1;
        af0[0] = f2bf(x0[0] * sfac); af0[1] = f2bf(x0[1] * sfac);
        af0[2] = f2bf(x0[2] * sfac); af0[3] = f2bf(x0[3] * sfac);
        af0[4] = f2bf(x1[0] * sfac); af0[5] = f2bf(x1[1] * sfac);
        af0[6] = f2bf(x1[2] * sfac); af0[7] = f2bf(x1[3] * sfac);
        af1[0] = f2bf(x2[0] * sfac); af1[1] = f2bf(x2[1] * sfac);
        af1[2] = f2bf(x2[2] * sfac); af1[3] = f2bf(x2[3] * sfac);
        af1[4] = f2bf(x3[0] * sfac); af1[5] = f2bf(x3[1] * sfac);
        af1[6] = f2bf(x3[2] * sfac); af1[7] = f2bf(x3[3] * sfac);

        f32x4 acc[4];
        #pragma unroll
        for (int c = 0; c < 4; ++c) {
            acc[c][0] = 0.f; acc[c][1] = 0.f; acc[c][2] = 0.f; acc[c][3] = 0.f;
            acc[c] = __builtin_amdgcn_mfma_f32_16x16x32_bf16(wf[c][0], af0, acc[c], 0, 0, 0);
            acc[c] = __builtin_amdgcn_mfma_f32_16x16x32_bf16(wf[c][1], af1, acc[c], 0, 0, 0);
        }

        // ---- +bias, two-pass LN in registers (R4/R6-verified)
        float pS = 0.f;
        #pragma unroll
        for (int c = 0; c < 4; ++c) {
            #pragma unroll
            for (int i = 0; i < 4; ++i) {
                acc[c][i] += bb[c][i];
                pS += acc[c][i];
            }
        }
        pS += __shfl_xor(pS, 16, 64);
        pS += __shfl_xor(pS, 32, 64);
        const float mu = pS * (1.0f / 64.0f);

        float qS = 0.f;
        #pragma unroll
        for (int c = 0; c < 4; ++c) {
            #pragma unroll
            for (int i = 0; i < 4; ++i) {
                const float d = acc[c][i] - mu;
                qS += d * d;
            }
        }
        qS += __shfl_xor(qS, 16, 64);
        qS += __shfl_xor(qS, 32, 64);
        const float rstd = 1.0f / sqrtf(qS * (1.0f / 64.0f) + LN_EPS);

        // ---- repack t into the CONSUMED x buffer (x already in registers).
        //      64-float rows + XOR swizzle col^((row&7)<<2): conflict-free
        //      write and read (R11/R12-verified).
        #pragma unroll
        for (int c = 0; c < 4; ++c)
            *reinterpret_cast<f32x4*>(
                Sb + l16 * 64 + ((c * 16 + lg * 4) ^ ((l16 & 7) << 2))) = acc[c];
        if (lg == 0) { muLds[wave][l16] = mu; rsLds[wave][l16] = rstd; }

        // ---- NT full-line stores: lane (l16,lg) -> row rl=k*4+lg, cols l16*4..+3
        const int rowb = b0 + sub * 16;
        #pragma unroll
        for (int k = 0; k < 4; ++k) {
            const int rl = k * 4 + lg;
            const f32x4 tv = *reinterpret_cast<const f32x4*>(
                Sb + rl * 64 + ((l16 * 4) ^ ((rl & 7) << 2)));
            const float m  = muLds[wave][rl];
            const float rs = rsLds[wave][rl];
            f32x4 o;
            #pragma unroll
            for (int i = 0; i < 4; ++i) {
                float v = (tv[i] - m) * rs * gg[i] + be[i];
                o[i] = v >= 0.f ? v : v * NEG_SLOPE;
            }
            __builtin_nontemporal_store(
                o, reinterpret_cast<f32x4*>(
                       out + ((size_t)(rowb + rl) * NNODES + node) * HID + l16 * 4));
        }

        // ---- recycle: epilogue ds_reads must retire before gll overwrites
        WAITL0();
        if (sub + 2 < SUBS) {
            STAGE(sub + 2, sub & 1);
        }
    }
#undef STAGE
}

extern "C" void kernel_launch(void* const* d_in, const int* in_sizes, int n_in,
                              void* d_out, int out_size, void* d_ws, size_t ws_size,
                              hipStream_t stream) {
    const float* x      = (const float*)d_in[0];
    const float* dec    = (const float*)d_in[1];
    const float* rec    = (const float*)d_in[2];
    const float* W      = (const float*)d_in[3];
    const float* bias   = (const float*)d_in[4];
    const float* gamma  = (const float*)d_in[5];
    const float* beta   = (const float*)d_in[6];
    const int*   scales = (const int*)d_in[7];
    float* out = (float*)d_out;

    const int blocks = (NNODES / NPB) * (BATCH / RPW);  // 128 * 8 = 1024
    wv_mfma11_kernel<<<blocks, 256, 0, stream>>>(
        x, dec, rec, W, bias, gamma, beta, scales, out);
}

// Round 14
// 97.494 us; speedup vs baseline: 1.4039x; 1.0003x over previous
//
#include <hip/hip_runtime.h>
#include <hip/hip_bf16.h>

#define BATCH 2048
#define NNODES 512
#define HID 64
#define LN_EPS 1e-5f
#define NEG_SLOPE 0.01f

#define NPB 4        // nodes per block (one per wave; waves fully independent)
#define SUBS 16      // 16-row subtiles per wave
#define RPW 256      // rows per wave = SUBS*16

typedef __attribute__((ext_vector_type(8))) short bf16x8;
typedef __attribute__((ext_vector_type(4))) float f32x4;

__device__ __forceinline__ short f2bf(float f) {
    union { __hip_bfloat16 h; short s; } u;
    u.h = __float2bfloat16(f);   // canonical RNE (R3/R4-verified)
    return u.s;
}

#define WAITV4() asm volatile("s_waitcnt vmcnt(4)" ::: "memory")
#define WAITV8() asm volatile("s_waitcnt vmcnt(8)" ::: "memory")
#define WAITL0() asm volatile("s_waitcnt lgkmcnt(0)" ::: "memory")

// v14 = R13 (97.5us, verified) + ONE change: mu/rstd broadcast via __shfl
// bpermutes instead of muLds/rsLds scalars. mu/rstd are identical across the
// 4 lanes sharing an l16 (shfl_xor{16,32} reduction), so row rl's stats live
// in lane rl; epilogue reads them with __shfl(.., k*4+lg). Deletes 512B of
// LDS -> exactly 32768B -> 5 blocks/CU (was 4), +25% resident waves.
// Everything else R13-verbatim (aliased t-repack, XOR swizzles, sfac on x
// path, bounds(256,3), vmcnt ledger {N=4 at sub 0/SUBS-1 else 8; lgkmcnt(0)
// before STAGE recycle}).
__global__ __launch_bounds__(256, 3) void wv_mfma12_kernel(
    const float* __restrict__ x,      // [B, N, H]
    const float* __restrict__ dec,    // [3, 4]
    const float* __restrict__ rec,    // [3, 4]
    const float* __restrict__ W,      // [N, H, H]
    const float* __restrict__ bias,   // [N, H]
    const float* __restrict__ gamma,  // [N, H]
    const float* __restrict__ beta,   // [N, H]
    const int*   __restrict__ scales, // [N]
    float* __restrict__ out)          // [B, N, H]
{
    __shared__ float xStage[NPB][2][1024];   // 2 x 4KB per wave; t aliased in

    const int tid  = threadIdx.x;
    const int wave = tid >> 6;
    const int lane = tid & 63;
    const int l16  = lane & 15;
    const int lg   = lane >> 4;      // 0..3

    const int ng   = blockIdx.x & 127;   // node-group minor (R7 lesson)
    const int rc   = blockIdx.x >> 7;    // 0..7 row chunk
    const int node = ng * NPB + wave;
    const int b0   = rc * RPW;

    const int   sc   = scales[node];
    const float sfac = dec[sc * 4 + 1] + rec[sc * 4 + 1];

// stage rows b0+(sub)*16..+15 into xStage[wave][buf]; lane j covers row
// k*4+(j>>4), 16B slot (j&15); source col pre-swizzled so LDS reads with the
// same XOR are bank-spread (rule #21 both-sides). 4 x gll_dwordx4 (1KB each).
#define STAGE(sub_, buf_)                                                     \
    {                                                                         \
        const int s4_ = (lane & 15) * 4;                                      \
        const int rb_ = lane >> 4;                                            \
        _Pragma("unroll")                                                     \
        for (int k_ = 0; k_ < 4; ++k_) {                                      \
            const int r_ = k_ * 4 + rb_;                                      \
            const float* g_ = x + (size_t)(b0 + (sub_) * 16 + r_) *           \
                                  (NNODES * HID) + node * HID +               \
                                  (s4_ ^ ((r_ & 7) << 2));                    \
            __builtin_amdgcn_global_load_lds(                                 \
                (const __attribute__((address_space(1))) void*)g_,            \
                (__attribute__((address_space(3))) void*)                     \
                    (&xStage[wave][buf_][0] + k_ * 256),                      \
                16, 0, 0);                                                    \
        }                                                                     \
    }

    // ---- prologue: W loads (16 dwordx4), then stage(0), stage(1)
    f32x4 wv[4][2][2];
    const float* Wn = W + (size_t)node * HID * HID;
    #pragma unroll
    for (int c = 0; c < 4; ++c) {
        #pragma unroll
        for (int s = 0; s < 2; ++s) {
            const float* p = Wn + (c * 16 + l16) * HID + s * 32 + lg * 8;
            wv[c][s][0] = *reinterpret_cast<const f32x4*>(p);
            wv[c][s][1] = *reinterpret_cast<const f32x4*>(p + 4);
        }
    }
    STAGE(0, 0);
    STAGE(1, 1);

    // ---- epilogue params
    f32x4 bb[4];
    #pragma unroll
    for (int c = 0; c < 4; ++c)
        bb[c] = *reinterpret_cast<const f32x4*>(bias + node * HID + c * 16 + lg * 4);
    const f32x4 gg = *reinterpret_cast<const f32x4*>(gamma + node * HID + l16 * 4);
    const f32x4 be = *reinterpret_cast<const f32x4*>(beta  + node * HID + l16 * 4);

    // ---- convert W once (compiler's own vmcnt wait covers the W loads)
    bf16x8 wf[4][2];
    #pragma unroll
    for (int c = 0; c < 4; ++c) {
        #pragma unroll
        for (int s = 0; s < 2; ++s) {
            const f32x4 w0 = wv[c][s][0], w1 = wv[c][s][1];
            bf16x8 f;
            f[0] = f2bf(w0[0]); f[1] = f2bf(w0[1]); f[2] = f2bf(w0[2]); f[3] = f2bf(w0[3]);
            f[4] = f2bf(w1[0]); f[5] = f2bf(w1[1]); f[6] = f2bf(w1[2]); f[7] = f2bf(w1[3]);
            wf[c][s] = f;
        }
    }

    const int ro = l16 * 64;           // x-phase LDS row offset (floats)
    const int sw = (l16 & 7) << 2;     // x-phase read-side XOR (floats)

    #pragma unroll
    for (int sub = 0; sub < SUBS; ++sub) {
        // counted wait: stage(sub) retired when <= N newer vmem ops remain
        if (sub == 0 || sub == SUBS - 1) { WAITV4(); } else { WAITV8(); }

        float* Sb = &xStage[wave][sub & 1][0];
        const f32x4 x0 = *reinterpret_cast<const f32x4*>(Sb + ro + ((lg * 8     ) ^ sw));
        const f32x4 x1 = *reinterpret_cast<const f32x4*>(Sb + ro + ((lg * 8 + 4 ) ^ sw));
        const f32x4 x2 = *reinterpret_cast<const f32x4*>(Sb + ro + ((lg * 8 + 32) ^ sw));
        const f32x4 x3 = *reinterpret_cast<const f32x4*>(Sb + ro + ((lg * 8 + 36) ^ sw));

        bf16x8 af0, af1;
        af0[0] = f2bf(x0[0] * sfac); af0[1] = f2bf(x0[1] * sfac);
        af0[2] = f2bf(x0[2] * sfac); af0[3] = f2bf(x0[3] * sfac);
        af0[4] = f2bf(x1[0] * sfac); af0[5] = f2bf(x1[1] * sfac);
        af0[6] = f2bf(x1[2] * sfac); af0[7] = f2bf(x1[3] * sfac);
        af1[0] = f2bf(x2[0] * sfac); af1[1] = f2bf(x2[1] * sfac);
        af1[2] = f2bf(x2[2] * sfac); af1[3] = f2bf(x2[3] * sfac);
        af1[4] = f2bf(x3[0] * sfac); af1[5] = f2bf(x3[1] * sfac);
        af1[6] = f2bf(x3[2] * sfac); af1[7] = f2bf(x3[3] * sfac);

        f32x4 acc[4];
        #pragma unroll
        for (int c = 0; c < 4; ++c) {
            acc[c][0] = 0.f; acc[c][1] = 0.f; acc[c][2] = 0.f; acc[c][3] = 0.f;
            acc[c] = __builtin_amdgcn_mfma_f32_16x16x32_bf16(wf[c][0], af0, acc[c], 0, 0, 0);
            acc[c] = __builtin_amdgcn_mfma_f32_16x16x32_bf16(wf[c][1], af1, acc[c], 0, 0, 0);
        }

        // ---- +bias, two-pass LN in registers (R4/R6-verified)
        float pS = 0.f;
        #pragma unroll
        for (int c = 0; c < 4; ++c) {
            #pragma unroll
            for (int i = 0; i < 4; ++i) {
                acc[c][i] += bb[c][i];
                pS += acc[c][i];
            }
        }
        pS += __shfl_xor(pS, 16, 64);
        pS += __shfl_xor(pS, 32, 64);
        const float mu = pS * (1.0f / 64.0f);

        float qS = 0.f;
        #pragma unroll
        for (int c = 0; c < 4; ++c) {
            #pragma unroll
            for (int i = 0; i < 4; ++i) {
                const float d = acc[c][i] - mu;
                qS += d * d;
            }
        }
        qS += __shfl_xor(qS, 16, 64);
        qS += __shfl_xor(qS, 32, 64);
        const float rstd = 1.0f / sqrtf(qS * (1.0f / 64.0f) + LN_EPS);

        // ---- repack t into the CONSUMED x buffer (x already in registers).
        //      64-float rows + XOR swizzle col^((row&7)<<2): conflict-free
        //      write and read (R11/R12-verified).
        #pragma unroll
        for (int c = 0; c < 4; ++c)
            *reinterpret_cast<f32x4*>(
                Sb + l16 * 64 + ((c * 16 + lg * 4) ^ ((l16 & 7) << 2))) = acc[c];

        // ---- NT full-line stores: lane (l16,lg) -> row rl=k*4+lg, cols
        //      l16*4..+3; mu/rstd of row rl fetched from lane rl via shfl
        //      (bpermute; identical across the 4 lanes sharing that l16).
        const int rowb = b0 + sub * 16;
        #pragma unroll
        for (int k = 0; k < 4; ++k) {
            const int rl = k * 4 + lg;
            const f32x4 tv = *reinterpret_cast<const f32x4*>(
                Sb + rl * 64 + ((l16 * 4) ^ ((rl & 7) << 2)));
            const float m  = __shfl(mu,   rl, 64);
            const float rs = __shfl(rstd, rl, 64);
            f32x4 o;
            #pragma unroll
            for (int i = 0; i < 4; ++i) {
                float v = (tv[i] - m) * rs * gg[i] + be[i];
                o[i] = v >= 0.f ? v : v * NEG_SLOPE;
            }
            __builtin_nontemporal_store(
                o, reinterpret_cast<f32x4*>(
                       out + ((size_t)(rowb + rl) * NNODES + node) * HID + l16 * 4));
        }

        // ---- recycle: epilogue ds_reads must retire before gll overwrites
        WAITL0();
        if (sub + 2 < SUBS) {
            STAGE(sub + 2, sub & 1);
        }
    }
#undef STAGE
}

extern "C" void kernel_launch(void* const* d_in, const int* in_sizes, int n_in,
                              void* d_out, int out_size, void* d_ws, size_t ws_size,
                              hipStream_t stream) {
    const float* x      = (const float*)d_in[0];
    const float* dec    = (const float*)d_in[1];
    const float* rec    = (const float*)d_in[2];
    const float* W      = (const float*)d_in[3];
    const float* bias   = (const float*)d_in[4];
    const float* gamma  = (const float*)d_in[5];
    const float* beta   = (const float*)d_in[6];
    const int*   scales = (const int*)d_in[7];
    float* out = (float*)d_out;

    const int blocks = (NNODES / NPB) * (BATCH / RPW);  // 128 * 8 = 1024
    wv_mfma12_kernel<<<blocks, 256, 0, stream>>>(
        x, dec, rec, W, bias, gamma, beta, scales, out);
}